// Round 13
// baseline (620.626 us; speedup 1.0000x reference)
//
#include <hip/hip_runtime.h>

#define N_G   15135
#define E_N   242160
#define BSZ   8
#define K_TOP 7568
#define NH    128
#define NBIN  65536
#define SUFS  65600

typedef float f4v __attribute__((ext_vector_type(4)));
typedef float f2v __attribute__((ext_vector_type(2)));

// ---------------- utility ----------------
__global__ void zero_kernel(int* __restrict__ p, int n) {
  int i = blockIdx.x * 1024 + threadIdx.x;
  if (i < n) p[i] = 0;
}

__global__ void count_kernel(const int* __restrict__ ei, int* __restrict__ cnt) {
  int e = blockIdx.x * 256 + threadIdx.x;
  if (e < E_N) atomicAdd(&cnt[ei[E_N + e]], 1);
}

// local scan over PADDED counts (pad to multiple of 8) + atomic ticket.
// rowdesc = (rowstart, padded_cnt, dinv). dinv uses the real count.
__global__ __launch_bounds__(1024) void scan_kernel(const int* __restrict__ cnt,
                                                    int* __restrict__ rowstart,
                                                    float* __restrict__ dinv,
                                                    int4* __restrict__ rowdesc,
                                                    int* __restrict__ gctr,
                                                    const float* __restrict__ topk_w,
                                                    float* __restrict__ scal) {
  __shared__ int buf[1024];
  __shared__ int base;
  int tid = threadIdx.x;
  int i = blockIdx.x * 1024 + tid;
  int v = (i < N_G) ? cnt[i] : 0;
  int vp = (v + 7) & ~7;  // padded length
  float di = 1.0f / sqrtf((float)(v + 1));
  if (i < N_G) dinv[i] = di;
  buf[tid] = vp;
  __syncthreads();
  for (int s = 1; s < 1024; s <<= 1) {
    int t = (tid >= s) ? buf[tid - s] : 0;
    __syncthreads();
    buf[tid] += t;
    __syncthreads();
  }
  if (tid == 1023) base = atomicAdd(gctr, buf[1023]);
  __syncthreads();
  if (i < N_G) {
    int rs = base + buf[tid] - vp;
    rowstart[i] = rs;
    rowdesc[i] = make_int4(rs, vp, __float_as_int(di), 0);
  }
  if (blockIdx.x == 0) {
    __shared__ float fbuf[512];
    if (tid < 512) {
      float w = (tid < 384) ? topk_w[tid] : 0.f;
      fbuf[tid] = w * w;
    }
    __syncthreads();
    for (int s = 256; s > 0; s >>= 1) {
      if (tid < s) fbuf[tid] += fbuf[tid + s];
      __syncthreads();
    }
    if (tid == 0) scal[0] = 1.0f / sqrtf(fbuf[0]);
  }
}

// csr packs (src, dinv[src]).
__global__ void fill_kernel(const int* __restrict__ ei, const int* __restrict__ rowstart,
                            const float* __restrict__ dinv, int* __restrict__ fillc,
                            int2* __restrict__ csr) {
  int e = blockIdx.x * 256 + threadIdx.x;
  if (e < E_N) {
    int s = ei[e], d = ei[E_N + e];
    int pos = rowstart[d] + atomicAdd(&fillc[d], 1);
    csr[pos] = make_int2(s, __float_as_int(dinv[s]));
  }
}

// dummy edges (src=0, w=0) fill the pad slots -> uniform 8-blocks, no tail code.
__global__ void pad_kernel(const int* __restrict__ cnt, const int4* __restrict__ rowdesc,
                           int2* __restrict__ csr) {
  int i = blockIdx.x * 256 + threadIdx.x;
  if (i < N_G) {
    int4 rd = rowdesc[i];
    int c = cnt[i];
    for (int q = c; q < rd.y; ++q) csr[rd.x + q] = make_int2(0, 0);
  }
}

// ---------------- dense matmul, batch-pinned blocks ----------------
template<int CIN, bool BR>
__global__ __launch_bounds__(256, 6) void mm_kernel(const float* __restrict__ A,
                                                    const float* __restrict__ W,
                                                    const float* __restrict__ bias,
                                                    float* __restrict__ out) {
  __shared__ float Bst[32][132];
  __shared__ float Ast2[32][68];
  int tid = threadIdx.x;
  int b = blockIdx.x & 7;
  int ib = blockIdx.x >> 3;
  int rb0 = b * N_G + ib * 64;
  int rmax = N_G - ib * 64;
  int c0 = (tid & 31) * 4;
  int r0 = (tid >> 5) * 8;
  float acc[8][4];
#pragma unroll
  for (int i = 0; i < 8; i++)
#pragma unroll
    for (int j = 0; j < 4; j++) acc[i][j] = 0.f;

  for (int k0 = 0; k0 < CIN; k0 += 32) {
    {
      int koff = (tid & 7) * 4;
      int row = tid >> 3;
#pragma unroll
      for (int p = 0; p < 2; ++p) {
        int r = row + p * 32;
        f4v v = {0.f, 0.f, 0.f, 0.f};
        if (r < rmax) v = __builtin_nontemporal_load((const f4v*)(A + (size_t)(rb0 + r) * CIN + k0 + koff));
        Ast2[koff + 0][r] = v.x; Ast2[koff + 1][r] = v.y;
        Ast2[koff + 2][r] = v.z; Ast2[koff + 3][r] = v.w;
      }
    }
    {
      int cc = (tid & 31) * 4;
      int kr = tid >> 5;
#pragma unroll
      for (int p = 0; p < 4; ++p) {
        int k = kr + p * 8;
        *(float4*)&Bst[k][cc] = *(const float4*)(W + (size_t)(k0 + k) * NH + cc);
      }
    }
    __syncthreads();
#pragma unroll 4
    for (int kk = 0; kk < 32; ++kk) {
      float a[8], bb[4];
      *(float4*)&a[0] = *(const float4*)&Ast2[kk][r0];
      *(float4*)&a[4] = *(const float4*)&Ast2[kk][r0 + 4];
      *(float4*)&bb[0] = *(const float4*)&Bst[kk][c0];
#pragma unroll
      for (int i = 0; i < 8; i++)
#pragma unroll
        for (int j = 0; j < 4; j++)
          acc[i][j] = fmaf(a[i], bb[j], acc[i][j]);
    }
    __syncthreads();
  }
  float b0 = 0.f, b1 = 0.f, b2 = 0.f, b3 = 0.f;
  if (BR) { b0 = bias[c0]; b1 = bias[c0+1]; b2 = bias[c0+2]; b3 = bias[c0+3]; }
#pragma unroll
  for (int i = 0; i < 8; i++) {
    int r = r0 + i;
    if (r < rmax) {
      float4 v;
      if (BR) {
        v.x = fmaxf(acc[i][0] + b0, 0.f); v.y = fmaxf(acc[i][1] + b1, 0.f);
        v.z = fmaxf(acc[i][2] + b2, 0.f); v.w = fmaxf(acc[i][3] + b3, 0.f);
      } else {
        v.x = acc[i][0]; v.y = acc[i][1]; v.z = acc[i][2]; v.w = acc[i][3];
      }
      *(float4*)(out + (size_t)(rb0 + r) * NH + c0) = v;
    }
  }
}

// ---------------- x-aggregation (64 ch), padded rows, 3-stage pipeline ----------------
__global__ __launch_bounds__(256) void agg64_kernel(const float* __restrict__ src,
                                                    const int2* __restrict__ csr,
                                                    const int4* __restrict__ rowdesc,
                                                    float* __restrict__ dst) {
  int b = blockIdx.x & 7;
  int chunk = blockIdx.x >> 3;
  int wave = threadIdx.x >> 6, lane = threadIdx.x & 63;
  int d = chunk * 4 + wave;
  if (d >= N_G) return;
  d = __builtin_amdgcn_readfirstlane(d);
  int4 rd = rowdesc[d];
  int e0 = rd.x, nb = rd.y >> 3;
  float dv = __int_as_float(rd.z);
  const float* sb = src + (size_t)b * N_G * 64;
  const int2* ce = csr + e0;
  float acc[8];
  acc[0] = dv * sb[(size_t)d * 64 + lane];
#pragma unroll
  for (int k = 1; k < 8; ++k) acc[k] = 0.f;
  if (nb >= 2) {
    int2 pA[8], pB[8]; float vA[8];
#pragma unroll
    for (int k = 0; k < 8; ++k) pA[k] = ce[k];
#pragma unroll
    for (int k = 0; k < 8; ++k) pB[k] = ce[8 + k];
#pragma unroll
    for (int k = 0; k < 8; ++k) vA[k] = sb[(size_t)pA[k].x * 64 + lane];
    int l = 16;
    for (int blk = 2; blk < nb; ++blk, l += 8) {
      int2 pC[8]; float vB[8];
#pragma unroll
      for (int k = 0; k < 8; ++k) pC[k] = ce[l + k];
#pragma unroll
      for (int k = 0; k < 8; ++k) vB[k] = sb[(size_t)pB[k].x * 64 + lane];
#pragma unroll
      for (int k = 0; k < 8; ++k) acc[k] = fmaf(__int_as_float(pA[k].y), vA[k], acc[k]);
#pragma unroll
      for (int k = 0; k < 8; ++k) { pA[k] = pB[k]; vA[k] = vB[k]; pB[k] = pC[k]; }
    }
    float vB[8];
#pragma unroll
    for (int k = 0; k < 8; ++k) vB[k] = sb[(size_t)pB[k].x * 64 + lane];
#pragma unroll
    for (int k = 0; k < 8; ++k) acc[k] = fmaf(__int_as_float(pA[k].y), vA[k], acc[k]);
#pragma unroll
    for (int k = 0; k < 8; ++k) acc[k] = fmaf(__int_as_float(pB[k].y), vB[k], acc[k]);
  } else if (nb == 1) {
    int2 pA[8]; float vA[8];
#pragma unroll
    for (int k = 0; k < 8; ++k) pA[k] = ce[k];
#pragma unroll
    for (int k = 0; k < 8; ++k) vA[k] = sb[(size_t)pA[k].x * 64 + lane];
#pragma unroll
    for (int k = 0; k < 8; ++k) acc[k] = fmaf(__int_as_float(pA[k].y), vA[k], acc[k]);
  }
  float s = ((acc[0] + acc[1]) + (acc[2] + acc[3])) + ((acc[4] + acc[5]) + (acc[6] + acc[7]));
  __builtin_nontemporal_store(dv * s, &dst[((size_t)b * N_G + d) * 64 + lane]);
}

// ---------------- full-width aggregation (128 ch, float2), padded, 3-stage ------------
__global__ __launch_bounds__(256) void agg_f2_kernel(const float* __restrict__ hw,
                                                     const int2* __restrict__ csr,
                                                     const int4* __restrict__ rowdesc,
                                                     const float* __restrict__ bias,
                                                     float* __restrict__ hout) {
  int b = blockIdx.x & 7;
  int chunk = blockIdx.x >> 3;
  int wave = threadIdx.x >> 6, lane = threadIdx.x & 63;
  int d = chunk * 4 + wave;
  if (d >= N_G) return;
  d = __builtin_amdgcn_readfirstlane(d);
  int4 rd = rowdesc[d];
  int e0 = rd.x, nb = rd.y >> 3;
  float dv = __int_as_float(rd.z);
  const f2v* sb = (const f2v*)(hw + (size_t)b * N_G * NH);
  const int2* ce = csr + e0;
  f2v self = sb[(size_t)d * 64 + lane];
  float ax[4], ay[4];
  ax[0] = dv * self.x; ay[0] = dv * self.y;
#pragma unroll
  for (int k = 1; k < 4; ++k) { ax[k] = 0.f; ay[k] = 0.f; }
  if (nb >= 2) {
    int2 pA[8], pB[8]; f2v vA[8];
#pragma unroll
    for (int k = 0; k < 8; ++k) pA[k] = ce[k];
#pragma unroll
    for (int k = 0; k < 8; ++k) pB[k] = ce[8 + k];
#pragma unroll
    for (int k = 0; k < 8; ++k) vA[k] = sb[(size_t)pA[k].x * 64 + lane];
    int l = 16;
    for (int blk = 2; blk < nb; ++blk, l += 8) {
      int2 pC[8]; f2v vB[8];
#pragma unroll
      for (int k = 0; k < 8; ++k) pC[k] = ce[l + k];
#pragma unroll
      for (int k = 0; k < 8; ++k) vB[k] = sb[(size_t)pB[k].x * 64 + lane];
#pragma unroll
      for (int k = 0; k < 8; ++k) {
        float w = __int_as_float(pA[k].y);
        ax[k & 3] = fmaf(w, vA[k].x, ax[k & 3]);
        ay[k & 3] = fmaf(w, vA[k].y, ay[k & 3]);
      }
#pragma unroll
      for (int k = 0; k < 8; ++k) { pA[k] = pB[k]; vA[k] = vB[k]; pB[k] = pC[k]; }
    }
    f2v vB[8];
#pragma unroll
    for (int k = 0; k < 8; ++k) vB[k] = sb[(size_t)pB[k].x * 64 + lane];
#pragma unroll
    for (int k = 0; k < 8; ++k) {
      float w = __int_as_float(pA[k].y);
      ax[k & 3] = fmaf(w, vA[k].x, ax[k & 3]);
      ay[k & 3] = fmaf(w, vA[k].y, ay[k & 3]);
    }
#pragma unroll
    for (int k = 0; k < 8; ++k) {
      float w = __int_as_float(pB[k].y);
      ax[k & 3] = fmaf(w, vB[k].x, ax[k & 3]);
      ay[k & 3] = fmaf(w, vB[k].y, ay[k & 3]);
    }
  } else if (nb == 1) {
    int2 pA[8]; f2v vA[8];
#pragma unroll
    for (int k = 0; k < 8; ++k) pA[k] = ce[k];
#pragma unroll
    for (int k = 0; k < 8; ++k) vA[k] = sb[(size_t)pA[k].x * 64 + lane];
#pragma unroll
    for (int k = 0; k < 8; ++k) {
      float w = __int_as_float(pA[k].y);
      ax[k & 3] = fmaf(w, vA[k].x, ax[k & 3]);
      ay[k & 3] = fmaf(w, vA[k].y, ay[k & 3]);
    }
  }
  float sx = (ax[0] + ax[1]) + (ax[2] + ax[3]);
  float sy = (ay[0] + ay[1]) + (ay[2] + ay[3]);
  const f2v* bb2 = (const f2v*)bias;
  f2v bb = bb2[lane];
  f2v r;
  r.x = fmaxf(fmaf(dv, sx, bb.x), 0.f);
  r.y = fmaxf(fmaf(dv, sy, bb.y), 0.f);
  __builtin_nontemporal_store(r, &((f2v*)hout)[((size_t)b * N_G + d) * 64 + lane]);
}

// ---------------- layer-3 full-width agg fused with score/fc dots + key + hist --------
__global__ __launch_bounds__(256) void agg_score_f2_kernel(const float* __restrict__ hw,
                                                           const int2* __restrict__ csr,
                                                           const int4* __restrict__ rowdesc,
                                                           const float* __restrict__ bias,
                                                           const float* __restrict__ h1,
                                                           const float* __restrict__ h2,
                                                           const float* __restrict__ topk_w,
                                                           const float* __restrict__ fcW,
                                                           const float* __restrict__ scal,
                                                           float* __restrict__ score,
                                                           float* __restrict__ d2a,
                                                           unsigned* __restrict__ keys,
                                                           int* __restrict__ hist) {
  int b = blockIdx.x & 7;
  int chunk = blockIdx.x >> 3;
  int wave = threadIdx.x >> 6, lane = threadIdx.x & 63;
  int d = chunk * 4 + wave;
  if (d >= N_G) return;
  d = __builtin_amdgcn_readfirstlane(d);
  int4 rd = rowdesc[d];
  int e0 = rd.x, nb = rd.y >> 3;
  float dv = __int_as_float(rd.z);
  const f2v* sb = (const f2v*)(hw + (size_t)b * N_G * NH);
  const int2* ce = csr + e0;
  size_t rbase = ((size_t)b * N_G + d) * 64 + lane;
  f2v u1 = __builtin_nontemporal_load(&((const f2v*)h1)[rbase]);
  f2v u2 = __builtin_nontemporal_load(&((const f2v*)h2)[rbase]);
  f2v self = sb[(size_t)d * 64 + lane];
  float ax[4], ay[4];
  ax[0] = dv * self.x; ay[0] = dv * self.y;
#pragma unroll
  for (int k = 1; k < 4; ++k) { ax[k] = 0.f; ay[k] = 0.f; }
  if (nb >= 2) {
    int2 pA[8], pB[8]; f2v vA[8];
#pragma unroll
    for (int k = 0; k < 8; ++k) pA[k] = ce[k];
#pragma unroll
    for (int k = 0; k < 8; ++k) pB[k] = ce[8 + k];
#pragma unroll
    for (int k = 0; k < 8; ++k) vA[k] = sb[(size_t)pA[k].x * 64 + lane];
    int l = 16;
    for (int blk = 2; blk < nb; ++blk, l += 8) {
      int2 pC[8]; f2v vB[8];
#pragma unroll
      for (int k = 0; k < 8; ++k) pC[k] = ce[l + k];
#pragma unroll
      for (int k = 0; k < 8; ++k) vB[k] = sb[(size_t)pB[k].x * 64 + lane];
#pragma unroll
      for (int k = 0; k < 8; ++k) {
        float w = __int_as_float(pA[k].y);
        ax[k & 3] = fmaf(w, vA[k].x, ax[k & 3]);
        ay[k & 3] = fmaf(w, vA[k].y, ay[k & 3]);
      }
#pragma unroll
      for (int k = 0; k < 8; ++k) { pA[k] = pB[k]; vA[k] = vB[k]; pB[k] = pC[k]; }
    }
    f2v vB[8];
#pragma unroll
    for (int k = 0; k < 8; ++k) vB[k] = sb[(size_t)pB[k].x * 64 + lane];
#pragma unroll
    for (int k = 0; k < 8; ++k) {
      float w = __int_as_float(pA[k].y);
      ax[k & 3] = fmaf(w, vA[k].x, ax[k & 3]);
      ay[k & 3] = fmaf(w, vA[k].y, ay[k & 3]);
    }
#pragma unroll
    for (int k = 0; k < 8; ++k) {
      float w = __int_as_float(pB[k].y);
      ax[k & 3] = fmaf(w, vB[k].x, ax[k & 3]);
      ay[k & 3] = fmaf(w, vB[k].y, ay[k & 3]);
    }
  } else if (nb == 1) {
    int2 pA[8]; f2v vA[8];
#pragma unroll
    for (int k = 0; k < 8; ++k) pA[k] = ce[k];
#pragma unroll
    for (int k = 0; k < 8; ++k) vA[k] = sb[(size_t)pA[k].x * 64 + lane];
#pragma unroll
    for (int k = 0; k < 8; ++k) {
      float w = __int_as_float(pA[k].y);
      ax[k & 3] = fmaf(w, vA[k].x, ax[k & 3]);
      ay[k & 3] = fmaf(w, vA[k].y, ay[k & 3]);
    }
  }
  float sx = (ax[0] + ax[1]) + (ax[2] + ax[3]);
  float sy = (ay[0] + ay[1]) + (ay[2] + ay[3]);
  const f2v* bb2 = (const f2v*)bias;
  f2v bb = bb2[lane];
  float rx = fmaxf(fmaf(dv, sx, bb.x), 0.f);
  float ry = fmaxf(fmaf(dv, sy, bb.y), 0.f);
  const f2v* tw2 = (const f2v*)topk_w;
  const f2v* fw2 = (const f2v*)fcW;
  f2v ta = tw2[lane * 3 + 0], tb = tw2[lane * 3 + 1], tc = tw2[lane * 3 + 2];
  f2v fa = fw2[lane * 3 + 0], fb = fw2[lane * 3 + 1], fc = fw2[lane * 3 + 2];
  float d1 = u1.x * ta.x + u2.x * ta.y + rx * tb.x
           + u1.y * tb.y + u2.y * tc.x + ry * tc.y;
  float d2 = u1.x * fa.x + u2.x * fa.y + rx * fb.x
           + u1.y * fb.y + u2.y * fc.x + ry * fc.y;
#pragma unroll
  for (int sh = 32; sh > 0; sh >>= 1) {
    d1 += __shfl_down(d1, sh);
    d2 += __shfl_down(d2, sh);
  }
  if (lane == 0) {
    int gw = b * N_G + d;
    float sc = tanhf(d1 * scal[0]);
    score[gw] = sc;
    d2a[gw] = d2;
    unsigned u = __float_as_uint(sc);
    unsigned k32 = (u & 0x80000000u) ? ~u : (u | 0x80000000u);
    keys[gw] = k32;
    atomicAdd(&hist[b * NBIN + (int)(k32 >> 16)], 1);
  }
}

// ---------------- per-batch suffix sums over 65536 bins ----------------
__global__ __launch_bounds__(1024) void suffix_kernel(const int* __restrict__ hist,
                                                      int* __restrict__ suf) {
  __shared__ int buf[1024];
  int b = blockIdx.x;
  const int* hb = hist + b * NBIN;
  int* sb = suf + b * SUFS;
  int t = threadIdx.x;
  int base = t * 64;
  int s = 0;
  for (int k = 0; k < 64; ++k) s += hb[base + k];
  buf[t] = s;
  __syncthreads();
  for (int off = 1; off < 1024; off <<= 1) {
    int v = (t + off < 1024) ? buf[t + off] : 0;
    __syncthreads();
    buf[t] += v;
    __syncthreads();
  }
  int acc = buf[t] - s;
  if (t == 0) sb[NBIN] = 0;
  for (int k = 63; k >= 0; --k) {
    acc += hb[base + k];
    sb[base + k] = acc;
  }
}

// ---------------- bucket scatter (consumes hist via atomicSub) ----------------
__global__ void scatter_kernel(const unsigned* __restrict__ keys, int* __restrict__ hist,
                               const int* __restrict__ suf, int2* __restrict__ bucket) {
  int b = blockIdx.y;
  int i = blockIdx.x * 256 + threadIdx.x;
  if (i >= N_G) return;
  unsigned k = keys[b * N_G + i];
  int bin = (int)(k >> 16);
  int old = atomicSub(&hist[b * NBIN + bin], 1);
  int pos = suf[b * SUFS + bin + 1] + old - 1;
  bucket[b * N_G + pos] = make_int2((int)k, i);
}

// ---------------- exact stable-descending rank + z scatter ----------------
__global__ void rank_z_kernel(const unsigned* __restrict__ keys, const int* __restrict__ suf,
                              const int2* __restrict__ bucket, const float* __restrict__ score,
                              const float* __restrict__ d2a, const float* __restrict__ fcb,
                              float* __restrict__ z) {
  int b = blockIdx.y;
  int i = blockIdx.x * 256 + threadIdx.x;
  if (i >= N_G) return;
  int gw = b * N_G + i;
  unsigned k = keys[gw];
  int bin = (int)(k >> 16);
  int lo = suf[b * SUFS + bin + 1];
  int hi = suf[b * SUFS + bin];
  int r = lo;
  const int2* bk = bucket + b * N_G;
  for (int p = lo; p < hi; ++p) {
    int2 e = bk[p];
    unsigned kj = (unsigned)e.x;
    r += (kj > k || (kj == k && e.y < i)) ? 1 : 0;
  }
  if (r < K_TOP) z[b * K_TOP + r] = fmaf(score[gw], d2a[gw], fcb[0]);
}

// ---------------- lin1 ----------------
__global__ __launch_bounds__(256) void lin1_kernel(const float* __restrict__ z,
                                                   const float* __restrict__ W,
                                                   float* __restrict__ hpre) {
  __shared__ float zb[237];
  int b = blockIdx.y, rs = blockIdx.x;
  int r0 = rs * 237;
  int rn = K_TOP - r0; if (rn > 237) rn = 237;
  for (int q = threadIdx.x; q < rn; q += 256) zb[q] = z[b * K_TOP + r0 + q];
  __syncthreads();
  int c = threadIdx.x;
  float a0 = 0.f, a1 = 0.f;
  for (int r = 0; r < rn; ++r) {
    float zz = zb[r];
    const float* wr = W + (size_t)(r0 + r) * 512;
    a0 = fmaf(zz, wr[c], a0);
    a1 = fmaf(zz, wr[c + 256], a1);
  }
  atomicAdd(&hpre[b * 512 + c], a0);
  atomicAdd(&hpre[b * 512 + c + 256], a1);
}

// ---------------- lin2 + log_softmax ----------------
__global__ __launch_bounds__(128) void lin2_kernel(const float* __restrict__ hpre,
                                                   const float* __restrict__ l1b,
                                                   const float* __restrict__ W2,
                                                   const float* __restrict__ l2b,
                                                   float* __restrict__ out) {
  int b = blockIdx.x, tid = threadIdx.x;
  float a0 = 0.f, a1 = 0.f;
  for (int j = tid; j < 512; j += 128) {
    float t = fmaxf(hpre[b * 512 + j] + l1b[j], 0.f);
    a0 = fmaf(t, W2[j * 2 + 0], a0);
    a1 = fmaf(t, W2[j * 2 + 1], a1);
  }
#pragma unroll
  for (int s = 32; s > 0; s >>= 1) {
    a0 += __shfl_down(a0, s);
    a1 += __shfl_down(a1, s);
  }
  __shared__ float red[2][2];
  if ((tid & 63) == 0) { red[tid >> 6][0] = a0; red[tid >> 6][1] = a1; }
  __syncthreads();
  if (tid == 0) {
    float l0 = red[0][0] + red[1][0] + l2b[0];
    float l1 = red[0][1] + red[1][1] + l2b[1];
    float m = fmaxf(l0, l1);
    float lse = m + logf(expf(l0 - m) + expf(l1 - m));
    out[b * 2 + 0] = l0 - lse;
    out[b * 2 + 1] = l1 - lse;
  }
}

extern "C" void kernel_launch(void* const* d_in, const int* in_sizes, int n_in,
                              void* d_out, int out_size, void* d_ws, size_t ws_size,
                              hipStream_t stream) {
  const float* x   = (const float*)d_in[0];
  const int*   ei  = (const int*)d_in[2];
  const float* W1  = (const float*)d_in[3];
  const float* b1  = (const float*)d_in[4];
  const float* W2  = (const float*)d_in[5];
  const float* b2  = (const float*)d_in[6];
  const float* W3  = (const float*)d_in[7];
  const float* b3  = (const float*)d_in[8];
  const float* tkw = (const float*)d_in[9];
  const float* fcW = (const float*)d_in[10];
  const float* fcb = (const float*)d_in[11];
  const float* l1W = (const float*)d_in[12];
  const float* l1b = (const float*)d_in[13];
  const float* l2W = (const float*)d_in[14];
  const float* l2b = (const float*)d_in[15];
  float* out = (float*)d_out;

  char* ws = (char*)d_ws;
  size_t off = 0;
  auto alloc = [&](size_t bytes) {
    char* p = ws + off;
    off += (bytes + 255) & ~(size_t)255;
    return p;
  };
  // zero-init region (contiguous): cnt, fillc, gctr, hpre, hist
  int*   cnt   = (int*)alloc(15136 * 4);
  int*   fillc = (int*)alloc(15136 * 4);
  int*   gctr  = (int*)alloc(256);
  float* hpre  = (float*)alloc(4096 * 4);
  int*   hist  = (int*)alloc((size_t)BSZ * NBIN * 4);
  // --- end zero region ---
  int*   rowstart = (int*)alloc(15136 * 4);
  float* dinv  = (float*)alloc(15136 * 4);
  int4*  rowdesc = (int4*)alloc(15136 * 16);
  float* scal  = (float*)alloc(64);
  float* z     = (float*)alloc((size_t)BSZ * K_TOP * 4);
  float* score = (float*)alloc(121088 * 4);
  float* d2a   = (float*)alloc(121088 * 4);
  unsigned* keys = (unsigned*)alloc(121088 * 4);
  int*   suf   = (int*)alloc((size_t)BSZ * SUFS * 4);
  int2*  bucket = (int2*)alloc(121088 * 8);
  int2*  csr   = (int2*)alloc((size_t)(E_N + 8 * N_G + 64) * 8);  // padded rows
  float* ax = (float*)alloc((size_t)BSZ * N_G * 64 * 4);
  float* hw = (float*)alloc((size_t)BSZ * N_G * NH * 4);
  float* h1 = (float*)alloc((size_t)BSZ * N_G * NH * 4);
  float* h2 = (float*)alloc((size_t)BSZ * N_G * NH * 4);
  (void)ws_size; (void)in_sizes; (void)n_in; (void)out_size;

  int zero_n = (int)(((char*)rowstart - (char*)cnt) / 4);
  zero_kernel<<<(zero_n + 1023) / 1024, 1024, 0, stream>>>(cnt, zero_n);
  count_kernel<<<(E_N + 255) / 256, 256, 0, stream>>>(ei, cnt);
  scan_kernel<<<(N_G + 1023) / 1024, 1024, 0, stream>>>(cnt, rowstart, dinv, rowdesc, gctr, tkw, scal);
  fill_kernel<<<(E_N + 255) / 256, 256, 0, stream>>>(ei, rowstart, dinv, fillc, csr);
  pad_kernel<<<(N_G + 255) / 256, 256, 0, stream>>>(cnt, rowdesc, csr);

  dim3 mmg(8 * 237);  // batch-pinned: b = blk&7
  int aggblocks = 8 * ((N_G + 3) / 4);

  // layer 1: agg(x) @ W1 (commutation)
  agg64_kernel<<<aggblocks, 256, 0, stream>>>(x, csr, rowdesc, ax);
  mm_kernel<64, true><<<mmg, 256, 0, stream>>>(ax, W1, b1, h1);
  // layer 2: full-width float2 aggregation
  mm_kernel<128, false><<<mmg, 256, 0, stream>>>(h1, W2, nullptr, hw);
  agg_f2_kernel<<<aggblocks, 256, 0, stream>>>(hw, csr, rowdesc, b2, h2);
  // layer 3: full-width agg fused with score/key/hist
  mm_kernel<128, false><<<mmg, 256, 0, stream>>>(h2, W3, nullptr, hw);
  agg_score_f2_kernel<<<aggblocks, 256, 0, stream>>>(hw, csr, rowdesc, b3, h1, h2,
                                                     tkw, fcW, scal, score, d2a, keys, hist);

  dim3 ng((N_G + 255) / 256, BSZ);
  suffix_kernel<<<BSZ, 1024, 0, stream>>>(hist, suf);
  scatter_kernel<<<ng, 256, 0, stream>>>(keys, hist, suf, bucket);
  rank_z_kernel<<<ng, 256, 0, stream>>>(keys, suf, bucket, score, d2a, fcb, z);

  dim3 l1g(32, BSZ);
  lin1_kernel<<<l1g, 256, 0, stream>>>(z, l1W, hpre);
  lin2_kernel<<<BSZ, 128, 0, stream>>>(hpre, l1b, l2W, l2b, out);
}

// Round 14
// 608.921 us; speedup vs baseline: 1.0192x; 1.0192x over previous
//
#include <hip/hip_runtime.h>

#define N_G   15135
#define E_N   242160
#define BSZ   8
#define K_TOP 7568
#define NH    128
#define NBIN  65536
#define SUFS  65600

typedef float f4v __attribute__((ext_vector_type(4)));
typedef float f2v __attribute__((ext_vector_type(2)));

// ---------------- utility ----------------
__global__ void zero_kernel(int* __restrict__ p, int n) {
  int i = blockIdx.x * 1024 + threadIdx.x;
  if (i < n) p[i] = 0;
}

__global__ void count_kernel(const int* __restrict__ ei, int* __restrict__ cnt) {
  int e = blockIdx.x * 256 + threadIdx.x;
  if (e < E_N) atomicAdd(&cnt[ei[E_N + e]], 1);
}

// local scan + atomic ticket; emits dinv, packed row descriptor (rowstart,cnt,dinv), scal.
__global__ __launch_bounds__(1024) void scan_kernel(const int* __restrict__ cnt,
                                                    int* __restrict__ rowstart,
                                                    float* __restrict__ dinv,
                                                    int4* __restrict__ rowdesc,
                                                    int* __restrict__ gctr,
                                                    const float* __restrict__ topk_w,
                                                    float* __restrict__ scal) {
  __shared__ int buf[1024];
  __shared__ int base;
  int tid = threadIdx.x;
  int i = blockIdx.x * 1024 + tid;
  int v = (i < N_G) ? cnt[i] : 0;
  float di = 1.0f / sqrtf((float)(v + 1));
  if (i < N_G) dinv[i] = di;
  buf[tid] = v;
  __syncthreads();
  for (int s = 1; s < 1024; s <<= 1) {
    int t = (tid >= s) ? buf[tid - s] : 0;
    __syncthreads();
    buf[tid] += t;
    __syncthreads();
  }
  if (tid == 1023) base = atomicAdd(gctr, buf[1023]);
  __syncthreads();
  if (i < N_G) {
    int rs = base + buf[tid] - v;
    rowstart[i] = rs;
    rowdesc[i] = make_int4(rs, v, __float_as_int(di), 0);
  }
  if (blockIdx.x == 0) {
    __shared__ float fbuf[512];
    if (tid < 512) {
      float w = (tid < 384) ? topk_w[tid] : 0.f;
      fbuf[tid] = w * w;
    }
    __syncthreads();
    for (int s = 256; s > 0; s >>= 1) {
      if (tid < s) fbuf[tid] += fbuf[tid + s];
      __syncthreads();
    }
    if (tid == 0) scal[0] = 1.0f / sqrtf(fbuf[0]);
  }
}

// csr packs (src, dinv[src]).
__global__ void fill_kernel(const int* __restrict__ ei, const int* __restrict__ rowstart,
                            const float* __restrict__ dinv, int* __restrict__ fillc,
                            int2* __restrict__ csr) {
  int e = blockIdx.x * 256 + threadIdx.x;
  if (e < E_N) {
    int s = ei[e], d = ei[E_N + e];
    int pos = rowstart[d] + atomicAdd(&fillc[d], 1);
    csr[pos] = make_int2(s, __float_as_int(dinv[s]));
  }
}

// ---------------- dense matmul, batch-pinned blocks ----------------
template<int CIN, bool BR>
__global__ __launch_bounds__(256, 6) void mm_kernel(const float* __restrict__ A,
                                                    const float* __restrict__ W,
                                                    const float* __restrict__ bias,
                                                    float* __restrict__ out) {
  __shared__ float Bst[32][132];
  __shared__ float Ast2[32][68];
  int tid = threadIdx.x;
  int b = blockIdx.x & 7;
  int ib = blockIdx.x >> 3;
  int rb0 = b * N_G + ib * 64;
  int rmax = N_G - ib * 64;
  int c0 = (tid & 31) * 4;
  int r0 = (tid >> 5) * 8;
  float acc[8][4];
#pragma unroll
  for (int i = 0; i < 8; i++)
#pragma unroll
    for (int j = 0; j < 4; j++) acc[i][j] = 0.f;

  for (int k0 = 0; k0 < CIN; k0 += 32) {
    {
      int koff = (tid & 7) * 4;
      int row = tid >> 3;
#pragma unroll
      for (int p = 0; p < 2; ++p) {
        int r = row + p * 32;
        f4v v = {0.f, 0.f, 0.f, 0.f};
        if (r < rmax) v = __builtin_nontemporal_load((const f4v*)(A + (size_t)(rb0 + r) * CIN + k0 + koff));
        Ast2[koff + 0][r] = v.x; Ast2[koff + 1][r] = v.y;
        Ast2[koff + 2][r] = v.z; Ast2[koff + 3][r] = v.w;
      }
    }
    {
      int cc = (tid & 31) * 4;
      int kr = tid >> 5;
#pragma unroll
      for (int p = 0; p < 4; ++p) {
        int k = kr + p * 8;
        *(float4*)&Bst[k][cc] = *(const float4*)(W + (size_t)(k0 + k) * NH + cc);
      }
    }
    __syncthreads();
#pragma unroll 4
    for (int kk = 0; kk < 32; ++kk) {
      float a[8], bb[4];
      *(float4*)&a[0] = *(const float4*)&Ast2[kk][r0];
      *(float4*)&a[4] = *(const float4*)&Ast2[kk][r0 + 4];
      *(float4*)&bb[0] = *(const float4*)&Bst[kk][c0];
#pragma unroll
      for (int i = 0; i < 8; i++)
#pragma unroll
        for (int j = 0; j < 4; j++)
          acc[i][j] = fmaf(a[i], bb[j], acc[i][j]);
    }
    __syncthreads();
  }
  float b0 = 0.f, b1 = 0.f, b2 = 0.f, b3 = 0.f;
  if (BR) { b0 = bias[c0]; b1 = bias[c0+1]; b2 = bias[c0+2]; b3 = bias[c0+3]; }
#pragma unroll
  for (int i = 0; i < 8; i++) {
    int r = r0 + i;
    if (r < rmax) {
      float4 v;
      if (BR) {
        v.x = fmaxf(acc[i][0] + b0, 0.f); v.y = fmaxf(acc[i][1] + b1, 0.f);
        v.z = fmaxf(acc[i][2] + b2, 0.f); v.w = fmaxf(acc[i][3] + b3, 0.f);
      } else {
        v.x = acc[i][0]; v.y = acc[i][1]; v.z = acc[i][2]; v.w = acc[i][3];
      }
      *(float4*)(out + (size_t)(rb0 + r) * NH + c0) = v;
    }
  }
}

// ---------------- x-aggregation (64 ch, float1 lanes), pipelined (R12 form) -----------
__global__ __launch_bounds__(256) void agg64_kernel(const float* __restrict__ src,
                                                    const int2* __restrict__ csr,
                                                    const int4* __restrict__ rowdesc,
                                                    float* __restrict__ dst) {
  int b = blockIdx.x & 7;
  int chunk = blockIdx.x >> 3;
  int wave = threadIdx.x >> 6, lane = threadIdx.x & 63;
  int d = chunk * 4 + wave;
  if (d >= N_G) return;
  d = __builtin_amdgcn_readfirstlane(d);
  int4 rd = rowdesc[d];
  int e0 = rd.x, n = rd.y;
  float dv = __int_as_float(rd.z);
  const float* sb = src + (size_t)b * N_G * 64;
  const int2* ce = csr + e0;
  float acc[8];
  acc[0] = dv * sb[(size_t)d * 64 + lane];
#pragma unroll
  for (int k = 1; k < 8; ++k) acc[k] = 0.f;
  int l = 0;
  if (n >= 8) {
    int2 pA[8]; float vA[8];
#pragma unroll
    for (int k = 0; k < 8; ++k) pA[k] = ce[k];
#pragma unroll
    for (int k = 0; k < 8; ++k) vA[k] = sb[(size_t)pA[k].x * 64 + lane];
    l = 8;
    for (; l + 8 <= n; l += 8) {
      int2 pB[8]; float vB[8];
#pragma unroll
      for (int k = 0; k < 8; ++k) pB[k] = ce[l + k];
#pragma unroll
      for (int k = 0; k < 8; ++k) vB[k] = sb[(size_t)pB[k].x * 64 + lane];
#pragma unroll
      for (int k = 0; k < 8; ++k) acc[k] = fmaf(__int_as_float(pA[k].y), vA[k], acc[k]);
#pragma unroll
      for (int k = 0; k < 8; ++k) { pA[k] = pB[k]; vA[k] = vB[k]; }
    }
#pragma unroll
    for (int k = 0; k < 8; ++k) acc[k] = fmaf(__int_as_float(pA[k].y), vA[k], acc[k]);
  }
  for (; l < n; ++l) {
    int2 p = ce[l];
    acc[0] = fmaf(__int_as_float(p.y), sb[(size_t)p.x * 64 + lane], acc[0]);
  }
  float s = ((acc[0] + acc[1]) + (acc[2] + acc[3])) + ((acc[4] + acc[5]) + (acc[6] + acc[7]));
  __builtin_nontemporal_store(dv * s, &dst[((size_t)b * N_G + d) * 64 + lane]);
}

// ---------------- full-width aggregation, TWO rows per wave, interleaved --------------
// Wave owns rows (d0, d0+1): steady loop issues 16 gathers (8 per row) before any use.
__global__ __launch_bounds__(256) void agg_f2_kernel(const float* __restrict__ hw,
                                                     const int2* __restrict__ csr,
                                                     const int4* __restrict__ rowdesc,
                                                     const float* __restrict__ bias,
                                                     float* __restrict__ hout) {
  int b = blockIdx.x & 7;
  int chunk = blockIdx.x >> 3;
  int wave = threadIdx.x >> 6, lane = threadIdx.x & 63;
  int d0 = chunk * 8 + wave * 2;
  if (d0 >= N_G) return;
  d0 = __builtin_amdgcn_readfirstlane(d0);
  int d1 = d0 + 1;
  int has1 = (d1 < N_G);
  int dB = has1 ? d1 : d0;
  int4 rdA = rowdesc[d0];
  int4 rdB = rowdesc[dB];
  int nA = rdA.y, nB = has1 ? rdB.y : 0;
  float dvA = __int_as_float(rdA.z);
  float dvB = __int_as_float(rdB.z);
  const f2v* sb = (const f2v*)(hw + (size_t)b * N_G * NH);
  const int2* ceA = csr + rdA.x;
  const int2* ceB = csr + rdB.x;
  f2v selfA = sb[(size_t)d0 * 64 + lane];
  f2v selfB = sb[(size_t)dB * 64 + lane];
  float axA[4], ayA[4], axB[4], ayB[4];
  axA[0] = dvA * selfA.x; ayA[0] = dvA * selfA.y;
  axB[0] = has1 ? dvB * selfB.x : 0.f;
  ayB[0] = has1 ? dvB * selfB.y : 0.f;
#pragma unroll
  for (int k = 1; k < 4; ++k) { axA[k] = 0.f; ayA[k] = 0.f; axB[k] = 0.f; ayB[k] = 0.f; }
  int lA = 0, lB = 0;
  while (lA + 8 <= nA && lB + 8 <= nB) {
    int2 pA[8], pB[8]; f2v vA[8], vB[8];
#pragma unroll
    for (int k = 0; k < 8; ++k) pA[k] = ceA[lA + k];
#pragma unroll
    for (int k = 0; k < 8; ++k) pB[k] = ceB[lB + k];
#pragma unroll
    for (int k = 0; k < 8; ++k) vA[k] = sb[(size_t)pA[k].x * 64 + lane];
#pragma unroll
    for (int k = 0; k < 8; ++k) vB[k] = sb[(size_t)pB[k].x * 64 + lane];
#pragma unroll
    for (int k = 0; k < 8; ++k) {
      float w = __int_as_float(pA[k].y);
      axA[k & 3] = fmaf(w, vA[k].x, axA[k & 3]);
      ayA[k & 3] = fmaf(w, vA[k].y, ayA[k & 3]);
    }
#pragma unroll
    for (int k = 0; k < 8; ++k) {
      float w = __int_as_float(pB[k].y);
      axB[k & 3] = fmaf(w, vB[k].x, axB[k & 3]);
      ayB[k & 3] = fmaf(w, vB[k].y, ayB[k & 3]);
    }
    lA += 8; lB += 8;
  }
  for (; lA + 8 <= nA; lA += 8) {
    int2 pA[8]; f2v vA[8];
#pragma unroll
    for (int k = 0; k < 8; ++k) pA[k] = ceA[lA + k];
#pragma unroll
    for (int k = 0; k < 8; ++k) vA[k] = sb[(size_t)pA[k].x * 64 + lane];
#pragma unroll
    for (int k = 0; k < 8; ++k) {
      float w = __int_as_float(pA[k].y);
      axA[k & 3] = fmaf(w, vA[k].x, axA[k & 3]);
      ayA[k & 3] = fmaf(w, vA[k].y, ayA[k & 3]);
    }
  }
  for (; lB + 8 <= nB; lB += 8) {
    int2 pB[8]; f2v vB[8];
#pragma unroll
    for (int k = 0; k < 8; ++k) pB[k] = ceB[lB + k];
#pragma unroll
    for (int k = 0; k < 8; ++k) vB[k] = sb[(size_t)pB[k].x * 64 + lane];
#pragma unroll
    for (int k = 0; k < 8; ++k) {
      float w = __int_as_float(pB[k].y);
      axB[k & 3] = fmaf(w, vB[k].x, axB[k & 3]);
      ayB[k & 3] = fmaf(w, vB[k].y, ayB[k & 3]);
    }
  }
  for (; lA < nA; ++lA) {
    int2 p = ceA[lA];
    f2v v = sb[(size_t)p.x * 64 + lane];
    float w = __int_as_float(p.y);
    axA[0] = fmaf(w, v.x, axA[0]); ayA[0] = fmaf(w, v.y, ayA[0]);
  }
  for (; lB < nB; ++lB) {
    int2 p = ceB[lB];
    f2v v = sb[(size_t)p.x * 64 + lane];
    float w = __int_as_float(p.y);
    axB[0] = fmaf(w, v.x, axB[0]); ayB[0] = fmaf(w, v.y, ayB[0]);
  }
  const f2v* bb2 = (const f2v*)bias;
  f2v bb = bb2[lane];
  {
    float sx = (axA[0] + axA[1]) + (axA[2] + axA[3]);
    float sy = (ayA[0] + ayA[1]) + (ayA[2] + ayA[3]);
    f2v r;
    r.x = fmaxf(fmaf(dvA, sx, bb.x), 0.f);
    r.y = fmaxf(fmaf(dvA, sy, bb.y), 0.f);
    __builtin_nontemporal_store(r, &((f2v*)hout)[((size_t)b * N_G + d0) * 64 + lane]);
  }
  if (has1) {
    float sx = (axB[0] + axB[1]) + (axB[2] + axB[3]);
    float sy = (ayB[0] + ayB[1]) + (ayB[2] + ayB[3]);
    f2v r;
    r.x = fmaxf(fmaf(dvB, sx, bb.x), 0.f);
    r.y = fmaxf(fmaf(dvB, sy, bb.y), 0.f);
    __builtin_nontemporal_store(r, &((f2v*)hout)[((size_t)b * N_G + d1) * 64 + lane]);
  }
}

// ---------------- layer-3: two rows per wave + fused score/key/hist -------------------
__global__ __launch_bounds__(256) void agg_score_f2_kernel(const float* __restrict__ hw,
                                                           const int2* __restrict__ csr,
                                                           const int4* __restrict__ rowdesc,
                                                           const float* __restrict__ bias,
                                                           const float* __restrict__ h1,
                                                           const float* __restrict__ h2,
                                                           const float* __restrict__ topk_w,
                                                           const float* __restrict__ fcW,
                                                           const float* __restrict__ scal,
                                                           float* __restrict__ score,
                                                           float* __restrict__ d2a,
                                                           unsigned* __restrict__ keys,
                                                           int* __restrict__ hist) {
  int b = blockIdx.x & 7;
  int chunk = blockIdx.x >> 3;
  int wave = threadIdx.x >> 6, lane = threadIdx.x & 63;
  int d0 = chunk * 8 + wave * 2;
  if (d0 >= N_G) return;
  d0 = __builtin_amdgcn_readfirstlane(d0);
  int d1 = d0 + 1;
  int has1 = (d1 < N_G);
  int dB = has1 ? d1 : d0;
  int4 rdA = rowdesc[d0];
  int4 rdB = rowdesc[dB];
  int nA = rdA.y, nB = has1 ? rdB.y : 0;
  float dvA = __int_as_float(rdA.z);
  float dvB = __int_as_float(rdB.z);
  const f2v* sb = (const f2v*)(hw + (size_t)b * N_G * NH);
  const int2* ceA = csr + rdA.x;
  const int2* ceB = csr + rdB.x;
  size_t rbA = ((size_t)b * N_G + d0) * 64 + lane;
  size_t rbB = ((size_t)b * N_G + dB) * 64 + lane;
  f2v u1A = __builtin_nontemporal_load(&((const f2v*)h1)[rbA]);
  f2v u2A = __builtin_nontemporal_load(&((const f2v*)h2)[rbA]);
  f2v u1B = __builtin_nontemporal_load(&((const f2v*)h1)[rbB]);
  f2v u2B = __builtin_nontemporal_load(&((const f2v*)h2)[rbB]);
  f2v selfA = sb[(size_t)d0 * 64 + lane];
  f2v selfB = sb[(size_t)dB * 64 + lane];
  float axA[4], ayA[4], axB[4], ayB[4];
  axA[0] = dvA * selfA.x; ayA[0] = dvA * selfA.y;
  axB[0] = has1 ? dvB * selfB.x : 0.f;
  ayB[0] = has1 ? dvB * selfB.y : 0.f;
#pragma unroll
  for (int k = 1; k < 4; ++k) { axA[k] = 0.f; ayA[k] = 0.f; axB[k] = 0.f; ayB[k] = 0.f; }
  int lA = 0, lB = 0;
  while (lA + 8 <= nA && lB + 8 <= nB) {
    int2 pA[8], pB[8]; f2v vA[8], vB[8];
#pragma unroll
    for (int k = 0; k < 8; ++k) pA[k] = ceA[lA + k];
#pragma unroll
    for (int k = 0; k < 8; ++k) pB[k] = ceB[lB + k];
#pragma unroll
    for (int k = 0; k < 8; ++k) vA[k] = sb[(size_t)pA[k].x * 64 + lane];
#pragma unroll
    for (int k = 0; k < 8; ++k) vB[k] = sb[(size_t)pB[k].x * 64 + lane];
#pragma unroll
    for (int k = 0; k < 8; ++k) {
      float w = __int_as_float(pA[k].y);
      axA[k & 3] = fmaf(w, vA[k].x, axA[k & 3]);
      ayA[k & 3] = fmaf(w, vA[k].y, ayA[k & 3]);
    }
#pragma unroll
    for (int k = 0; k < 8; ++k) {
      float w = __int_as_float(pB[k].y);
      axB[k & 3] = fmaf(w, vB[k].x, axB[k & 3]);
      ayB[k & 3] = fmaf(w, vB[k].y, ayB[k & 3]);
    }
    lA += 8; lB += 8;
  }
  for (; lA + 8 <= nA; lA += 8) {
    int2 pA[8]; f2v vA[8];
#pragma unroll
    for (int k = 0; k < 8; ++k) pA[k] = ceA[lA + k];
#pragma unroll
    for (int k = 0; k < 8; ++k) vA[k] = sb[(size_t)pA[k].x * 64 + lane];
#pragma unroll
    for (int k = 0; k < 8; ++k) {
      float w = __int_as_float(pA[k].y);
      axA[k & 3] = fmaf(w, vA[k].x, axA[k & 3]);
      ayA[k & 3] = fmaf(w, vA[k].y, ayA[k & 3]);
    }
  }
  for (; lB + 8 <= nB; lB += 8) {
    int2 pB[8]; f2v vB[8];
#pragma unroll
    for (int k = 0; k < 8; ++k) pB[k] = ceB[lB + k];
#pragma unroll
    for (int k = 0; k < 8; ++k) vB[k] = sb[(size_t)pB[k].x * 64 + lane];
#pragma unroll
    for (int k = 0; k < 8; ++k) {
      float w = __int_as_float(pB[k].y);
      axB[k & 3] = fmaf(w, vB[k].x, axB[k & 3]);
      ayB[k & 3] = fmaf(w, vB[k].y, ayB[k & 3]);
    }
  }
  for (; lA < nA; ++lA) {
    int2 p = ceA[lA];
    f2v v = sb[(size_t)p.x * 64 + lane];
    float w = __int_as_float(p.y);
    axA[0] = fmaf(w, v.x, axA[0]); ayA[0] = fmaf(w, v.y, ayA[0]);
  }
  for (; lB < nB; ++lB) {
    int2 p = ceB[lB];
    f2v v = sb[(size_t)p.x * 64 + lane];
    float w = __int_as_float(p.y);
    axB[0] = fmaf(w, v.x, axB[0]); ayB[0] = fmaf(w, v.y, ayB[0]);
  }
  const f2v* bb2 = (const f2v*)bias;
  f2v bb = bb2[lane];
  float rxA = fmaxf(fmaf(dvA, (axA[0] + axA[1]) + (axA[2] + axA[3]), bb.x), 0.f);
  float ryA = fmaxf(fmaf(dvA, (ayA[0] + ayA[1]) + (ayA[2] + ayA[3]), bb.y), 0.f);
  float rxB = fmaxf(fmaf(dvB, (axB[0] + axB[1]) + (axB[2] + axB[3]), bb.x), 0.f);
  float ryB = fmaxf(fmaf(dvB, (ayB[0] + ayB[1]) + (ayB[2] + ayB[3]), bb.y), 0.f);
  const f2v* tw2 = (const f2v*)topk_w;
  const f2v* fw2 = (const f2v*)fcW;
  f2v ta = tw2[lane * 3 + 0], tb = tw2[lane * 3 + 1], tc = tw2[lane * 3 + 2];
  f2v fa = fw2[lane * 3 + 0], fb = fw2[lane * 3 + 1], fc = fw2[lane * 3 + 2];
  float d1A = u1A.x * ta.x + u2A.x * ta.y + rxA * tb.x
            + u1A.y * tb.y + u2A.y * tc.x + ryA * tc.y;
  float d2A = u1A.x * fa.x + u2A.x * fa.y + rxA * fb.x
            + u1A.y * fb.y + u2A.y * fc.x + ryA * fc.y;
  float d1B = u1B.x * ta.x + u2B.x * ta.y + rxB * tb.x
            + u1B.y * tb.y + u2B.y * tc.x + ryB * tc.y;
  float d2B = u1B.x * fa.x + u2B.x * fa.y + rxB * fb.x
            + u1B.y * fb.y + u2B.y * fc.x + ryB * fc.y;
#pragma unroll
  for (int sh = 32; sh > 0; sh >>= 1) {
    d1A += __shfl_down(d1A, sh);
    d2A += __shfl_down(d2A, sh);
    d1B += __shfl_down(d1B, sh);
    d2B += __shfl_down(d2B, sh);
  }
  if (lane == 0) {
    {
      int gw = b * N_G + d0;
      float sc = tanhf(d1A * scal[0]);
      score[gw] = sc;
      d2a[gw] = d2A;
      unsigned u = __float_as_uint(sc);
      unsigned k32 = (u & 0x80000000u) ? ~u : (u | 0x80000000u);
      keys[gw] = k32;
      atomicAdd(&hist[b * NBIN + (int)(k32 >> 16)], 1);
    }
    if (has1) {
      int gw = b * N_G + d1;
      float sc = tanhf(d1B * scal[0]);
      score[gw] = sc;
      d2a[gw] = d2B;
      unsigned u = __float_as_uint(sc);
      unsigned k32 = (u & 0x80000000u) ? ~u : (u | 0x80000000u);
      keys[gw] = k32;
      atomicAdd(&hist[b * NBIN + (int)(k32 >> 16)], 1);
    }
  }
}

// ---------------- per-batch suffix sums over 65536 bins ----------------
__global__ __launch_bounds__(1024) void suffix_kernel(const int* __restrict__ hist,
                                                      int* __restrict__ suf) {
  __shared__ int buf[1024];
  int b = blockIdx.x;
  const int* hb = hist + b * NBIN;
  int* sb = suf + b * SUFS;
  int t = threadIdx.x;
  int base = t * 64;
  int s = 0;
  for (int k = 0; k < 64; ++k) s += hb[base + k];
  buf[t] = s;
  __syncthreads();
  for (int off = 1; off < 1024; off <<= 1) {
    int v = (t + off < 1024) ? buf[t + off] : 0;
    __syncthreads();
    buf[t] += v;
    __syncthreads();
  }
  int acc = buf[t] - s;
  if (t == 0) sb[NBIN] = 0;
  for (int k = 63; k >= 0; --k) {
    acc += hb[base + k];
    sb[base + k] = acc;
  }
}

// ---------------- bucket scatter (consumes hist via atomicSub) ----------------
__global__ void scatter_kernel(const unsigned* __restrict__ keys, int* __restrict__ hist,
                               const int* __restrict__ suf, int2* __restrict__ bucket) {
  int b = blockIdx.y;
  int i = blockIdx.x * 256 + threadIdx.x;
  if (i >= N_G) return;
  unsigned k = keys[b * N_G + i];
  int bin = (int)(k >> 16);
  int old = atomicSub(&hist[b * NBIN + bin], 1);
  int pos = suf[b * SUFS + bin + 1] + old - 1;
  bucket[b * N_G + pos] = make_int2((int)k, i);
}

// ---------------- exact stable-descending rank + z scatter ----------------
__global__ void rank_z_kernel(const unsigned* __restrict__ keys, const int* __restrict__ suf,
                              const int2* __restrict__ bucket, const float* __restrict__ score,
                              const float* __restrict__ d2a, const float* __restrict__ fcb,
                              float* __restrict__ z) {
  int b = blockIdx.y;
  int i = blockIdx.x * 256 + threadIdx.x;
  if (i >= N_G) return;
  int gw = b * N_G + i;
  unsigned k = keys[gw];
  int bin = (int)(k >> 16);
  int lo = suf[b * SUFS + bin + 1];
  int hi = suf[b * SUFS + bin];
  int r = lo;
  const int2* bk = bucket + b * N_G;
  for (int p = lo; p < hi; ++p) {
    int2 e = bk[p];
    unsigned kj = (unsigned)e.x;
    r += (kj > k || (kj == k && e.y < i)) ? 1 : 0;
  }
  if (r < K_TOP) z[b * K_TOP + r] = fmaf(score[gw], d2a[gw], fcb[0]);
}

// ---------------- lin1 ----------------
__global__ __launch_bounds__(256) void lin1_kernel(const float* __restrict__ z,
                                                   const float* __restrict__ W,
                                                   float* __restrict__ hpre) {
  __shared__ float zb[237];
  int b = blockIdx.y, rs = blockIdx.x;
  int r0 = rs * 237;
  int rn = K_TOP - r0; if (rn > 237) rn = 237;
  for (int q = threadIdx.x; q < rn; q += 256) zb[q] = z[b * K_TOP + r0 + q];
  __syncthreads();
  int c = threadIdx.x;
  float a0 = 0.f, a1 = 0.f;
  for (int r = 0; r < rn; ++r) {
    float zz = zb[r];
    const float* wr = W + (size_t)(r0 + r) * 512;
    a0 = fmaf(zz, wr[c], a0);
    a1 = fmaf(zz, wr[c + 256], a1);
  }
  atomicAdd(&hpre[b * 512 + c], a0);
  atomicAdd(&hpre[b * 512 + c + 256], a1);
}

// ---------------- lin2 + log_softmax ----------------
__global__ __launch_bounds__(128) void lin2_kernel(const float* __restrict__ hpre,
                                                   const float* __restrict__ l1b,
                                                   const float* __restrict__ W2,
                                                   const float* __restrict__ l2b,
                                                   float* __restrict__ out) {
  int b = blockIdx.x, tid = threadIdx.x;
  float a0 = 0.f, a1 = 0.f;
  for (int j = tid; j < 512; j += 128) {
    float t = fmaxf(hpre[b * 512 + j] + l1b[j], 0.f);
    a0 = fmaf(t, W2[j * 2 + 0], a0);
    a1 = fmaf(t, W2[j * 2 + 1], a1);
  }
#pragma unroll
  for (int s = 32; s > 0; s >>= 1) {
    a0 += __shfl_down(a0, s);
    a1 += __shfl_down(a1, s);
  }
  __shared__ float red[2][2];
  if ((tid & 63) == 0) { red[tid >> 6][0] = a0; red[tid >> 6][1] = a1; }
  __syncthreads();
  if (tid == 0) {
    float l0 = red[0][0] + red[1][0] + l2b[0];
    float l1 = red[0][1] + red[1][1] + l2b[1];
    float m = fmaxf(l0, l1);
    float lse = m + logf(expf(l0 - m) + expf(l1 - m));
    out[b * 2 + 0] = l0 - lse;
    out[b * 2 + 1] = l1 - lse;
  }
}

extern "C" void kernel_launch(void* const* d_in, const int* in_sizes, int n_in,
                              void* d_out, int out_size, void* d_ws, size_t ws_size,
                              hipStream_t stream) {
  const float* x   = (const float*)d_in[0];
  const int*   ei  = (const int*)d_in[2];
  const float* W1  = (const float*)d_in[3];
  const float* b1  = (const float*)d_in[4];
  const float* W2  = (const float*)d_in[5];
  const float* b2  = (const float*)d_in[6];
  const float* W3  = (const float*)d_in[7];
  const float* b3  = (const float*)d_in[8];
  const float* tkw = (const float*)d_in[9];
  const float* fcW = (const float*)d_in[10];
  const float* fcb = (const float*)d_in[11];
  const float* l1W = (const float*)d_in[12];
  const float* l1b = (const float*)d_in[13];
  const float* l2W = (const float*)d_in[14];
  const float* l2b = (const float*)d_in[15];
  float* out = (float*)d_out;

  char* ws = (char*)d_ws;
  size_t off = 0;
  auto alloc = [&](size_t bytes) {
    char* p = ws + off;
    off += (bytes + 255) & ~(size_t)255;
    return p;
  };
  // zero-init region (contiguous): cnt, fillc, gctr, hpre, hist
  int*   cnt   = (int*)alloc(15136 * 4);
  int*   fillc = (int*)alloc(15136 * 4);
  int*   gctr  = (int*)alloc(256);
  float* hpre  = (float*)alloc(4096 * 4);
  int*   hist  = (int*)alloc((size_t)BSZ * NBIN * 4);
  // --- end zero region ---
  int*   rowstart = (int*)alloc(15136 * 4);
  float* dinv  = (float*)alloc(15136 * 4);
  int4*  rowdesc = (int4*)alloc(15136 * 16);
  float* scal  = (float*)alloc(64);
  float* z     = (float*)alloc((size_t)BSZ * K_TOP * 4);
  float* score = (float*)alloc(121088 * 4);
  float* d2a   = (float*)alloc(121088 * 4);
  unsigned* keys = (unsigned*)alloc(121088 * 4);
  int*   suf   = (int*)alloc((size_t)BSZ * SUFS * 4);
  int2*  bucket = (int2*)alloc(121088 * 8);
  int2*  csr   = (int2*)alloc((size_t)E_N * 8);
  float* ax = (float*)alloc((size_t)BSZ * N_G * 64 * 4);
  float* hw = (float*)alloc((size_t)BSZ * N_G * NH * 4);
  float* h1 = (float*)alloc((size_t)BSZ * N_G * NH * 4);
  float* h2 = (float*)alloc((size_t)BSZ * N_G * NH * 4);
  (void)ws_size; (void)in_sizes; (void)n_in; (void)out_size;

  int zero_n = (int)(((char*)rowstart - (char*)cnt) / 4);
  zero_kernel<<<(zero_n + 1023) / 1024, 1024, 0, stream>>>(cnt, zero_n);
  count_kernel<<<(E_N + 255) / 256, 256, 0, stream>>>(ei, cnt);
  scan_kernel<<<(N_G + 1023) / 1024, 1024, 0, stream>>>(cnt, rowstart, dinv, rowdesc, gctr, tkw, scal);
  fill_kernel<<<(E_N + 255) / 256, 256, 0, stream>>>(ei, rowstart, dinv, fillc, csr);

  dim3 mmg(8 * 237);  // batch-pinned: b = blk&7
  int aggblocks  = 8 * ((N_G + 3) / 4);   // 1 row/wave kernels
  int aggblocks2 = 8 * ((N_G + 7) / 8);   // 2 rows/wave kernels

  // layer 1: agg(x) @ W1 (commutation)
  agg64_kernel<<<aggblocks, 256, 0, stream>>>(x, csr, rowdesc, ax);
  mm_kernel<64, true><<<mmg, 256, 0, stream>>>(ax, W1, b1, h1);
  // layer 2: full-width float2 aggregation, 2 rows/wave
  mm_kernel<128, false><<<mmg, 256, 0, stream>>>(h1, W2, nullptr, hw);
  agg_f2_kernel<<<aggblocks2, 256, 0, stream>>>(hw, csr, rowdesc, b2, h2);
  // layer 3: full-width agg fused with score/key/hist, 2 rows/wave
  mm_kernel<128, false><<<mmg, 256, 0, stream>>>(h2, W3, nullptr, hw);
  agg_score_f2_kernel<<<aggblocks2, 256, 0, stream>>>(hw, csr, rowdesc, b3, h1, h2,
                                                      tkw, fcW, scal, score, d2a, keys, hist);

  dim3 ng((N_G + 255) / 256, BSZ);
  suffix_kernel<<<BSZ, 1024, 0, stream>>>(hist, suf);
  scatter_kernel<<<ng, 256, 0, stream>>>(keys, hist, suf, bucket);
  rank_z_kernel<<<ng, 256, 0, stream>>>(keys, suf, bucket, score, d2a, fcb, z);

  dim3 l1g(32, BSZ);
  lin1_kernel<<<l1g, 256, 0, stream>>>(z, l1W, hpre);
  lin2_kernel<<<BSZ, 128, 0, stream>>>(hpre, l1b, l2W, l2b, out);
}